// Round 1
// baseline (461.165 us; speedup 1.0000x reference)
//
#include <hip/hip_runtime.h>

// YOLO loss: N=8192, S=14, B=2, C=20. ncells = N*S*S = 1,605,632.
// d_in[0] pred (ncells*30 f32), d_in[1] tbox (ncells*4 f32),
// d_in[2] tcls (ncells*20 f32), d_in[3] mask (ncells, dtype detected at runtime)
// d_out: 5 f32 = [total, reg, contain, noobj, cls] / N

#define L_COORD 5.0f
#define L_NOOBJ 0.5f

// ws layout: float acc[4] = {reg, contain, noobj, cls} at offset 0; int flag at offset 32.

__global__ void detect_mask_kernel(const unsigned int* __restrict__ w, int nwords,
                                   float* __restrict__ acc, int* __restrict__ flag) {
    __shared__ int s_int, s_flt;
    if (threadIdx.x == 0) {
        s_int = 1; s_flt = 1;
        acc[0] = 0.f; acc[1] = 0.f; acc[2] = 0.f; acc[3] = 0.f;
    }
    __syncthreads();
    int okInt = 1, okFlt = 1;
    for (int i = threadIdx.x; i < nwords; i += blockDim.x) {
        unsigned int v = w[i];
        okInt = okInt && (v == 0u || v == 1u);
        okFlt = okFlt && (v == 0u || v == 0x3F800000u);
    }
    if (!okInt) atomicAnd(&s_int, 0);
    if (!okFlt) atomicAnd(&s_flt, 0);
    __syncthreads();
    if (threadIdx.x == 0) *flag = s_int ? 1 : (s_flt ? 2 : 0);
}

__launch_bounds__(256)
__global__ void yolo_loss_kernel(const float* __restrict__ pred,
                                 const float* __restrict__ tbox,
                                 const float* __restrict__ tcls,
                                 const void* __restrict__ mask,
                                 const int* __restrict__ flag_p,
                                 float* __restrict__ acc,
                                 int ncells) {
    const int flg = *flag_p;                 // uniform across grid
    const float invS = 1.0f / 14.0f;
    float a_reg = 0.f, a_con = 0.f, a_noo = 0.f, a_cls = 0.f;
    const int stride = gridDim.x * blockDim.x;
    for (int c = blockIdx.x * blockDim.x + threadIdx.x; c < ncells; c += stride) {
        float f;
        if (flg == 1)      f = (((const int*)mask)[c] != 0) ? 1.0f : 0.0f;
        else if (flg == 2) f = ((const float*)mask)[c];
        else               f = (((const unsigned char*)mask)[c] != 0) ? 1.0f : 0.0f;

        // pred boxes: 10 floats at cell*30 (120B/cell -> 8B aligned)
        const float2* pb = (const float2*)(pred + (size_t)c * 30);
        float2 q0 = pb[0], q1 = pb[1], q2 = pb[2], q3 = pb[3], q4 = pb[4];
        // box0: x q0.x, y q0.y, w q1.x, h q1.y, conf q2.x
        // box1: x q2.y, y q3.x, w q3.y, h q4.x, conf q4.y
        const float cf0 = q2.x, cf1 = q4.y;
        a_noo += (1.0f - f) * (cf0 * cf0 + cf1 * cf1);

        if (f != 0.0f) {
            // class loss: pred[10..29] vs tcls[0..19]
            const float4* tc4 = (const float4*)(tcls + (size_t)c * 20);   // 80B/cell -> 16B aligned
            const float2* pc2 = (const float2*)(pred + (size_t)c * 30 + 10);
            float cl = 0.f;
            #pragma unroll
            for (int i = 0; i < 5; ++i) {
                float4 t = tc4[i];
                float2 a = pc2[2 * i], b = pc2[2 * i + 1];
                float d0 = a.x - t.x, d1 = a.y - t.y, d2 = b.x - t.z, d3 = b.y - t.w;
                cl += d0 * d0 + d1 * d1 + d2 * d2 + d3 * d3;
            }
            a_cls += f * cl;

            float4 tb = ((const float4*)tbox)[c];                         // 16B/cell
            float tx1 = tb.x * invS - 0.5f * tb.z;
            float ty1 = tb.y * invS - 0.5f * tb.w;
            float tx2 = tb.x * invS + 0.5f * tb.z;
            float ty2 = tb.y * invS + 0.5f * tb.w;
            float ta  = (tx2 - tx1) * (ty2 - ty1);

            float px0 = q0.x, py0 = q0.y, pw0 = q1.x, ph0 = q1.y;
            float px1 = q2.y, py1 = q3.x, pw1 = q3.y, ph1 = q4.x;

            // IoU box 0
            float x1 = px0 * invS - 0.5f * pw0, y1 = py0 * invS - 0.5f * ph0;
            float x2 = px0 * invS + 0.5f * pw0, y2 = py0 * invS + 0.5f * ph0;
            float lx = fmaxf(x1, tx1), ly = fmaxf(y1, ty1);
            float rx = fminf(x2, tx2), ry = fminf(y2, ty2);
            float wx = fmaxf(rx - lx, 0.f), wy = fmaxf(ry - ly, 0.f);
            float inter = wx * wy;
            float pa = (x2 - x1) * (y2 - y1);
            float iou0 = inter / (pa + ta - inter);
            // IoU box 1
            x1 = px1 * invS - 0.5f * pw1; y1 = py1 * invS - 0.5f * ph1;
            x2 = px1 * invS + 0.5f * pw1; y2 = py1 * invS + 0.5f * ph1;
            lx = fmaxf(x1, tx1); ly = fmaxf(y1, ty1);
            rx = fminf(x2, tx2); ry = fminf(y2, ty2);
            wx = fmaxf(rx - lx, 0.f); wy = fmaxf(ry - ly, 0.f);
            inter = wx * wy;
            pa = (x2 - x1) * (y2 - y1);
            float iou1 = inter / (pa + ta - inter);

            // jnp.argmax: first index on tie -> best=1 only if strictly greater
            int best = (iou1 > iou0) ? 1 : 0;
            float miou = fmaxf(iou0, iou1);

            float bx = best ? px1 : px0, by = best ? py1 : py0;
            float bw = best ? pw1 : pw0, bh = best ? ph1 : ph0;
            float bc = best ? cf1 : cf0;

            float dx = bx - tb.x, dy = by - tb.y;
            float sw = sqrtf(fmaxf(bw, 0.f)) - sqrtf(fmaxf(tb.z, 0.f));
            float sh = sqrtf(fmaxf(bh, 0.f)) - sqrtf(fmaxf(tb.w, 0.f));
            a_reg += f * (dx * dx + dy * dy + sw * sw + sh * sh);
            float dc = bc - miou;
            a_con += f * dc * dc;
        }
    }

    // wave reduce (64 lanes)
    #pragma unroll
    for (int off = 32; off > 0; off >>= 1) {
        a_reg += __shfl_down(a_reg, off, 64);
        a_con += __shfl_down(a_con, off, 64);
        a_noo += __shfl_down(a_noo, off, 64);
        a_cls += __shfl_down(a_cls, off, 64);
    }
    if ((threadIdx.x & 63) == 0) {
        atomicAdd(&acc[0], a_reg);
        atomicAdd(&acc[1], a_con);
        atomicAdd(&acc[2], a_noo);
        atomicAdd(&acc[3], a_cls);
    }
}

__global__ void finalize_kernel(const float* __restrict__ acc, float* __restrict__ out, float inv_n) {
    if (threadIdx.x == 0) {
        float reg = acc[0], con = acc[1], noo = acc[2], cls = acc[3];
        float total = cls + L_NOOBJ * noo + L_COORD * reg + con;
        out[0] = total * inv_n;
        out[1] = reg   * inv_n;
        out[2] = con   * inv_n;
        out[3] = noo   * inv_n;
        out[4] = cls   * inv_n;
    }
}

extern "C" void kernel_launch(void* const* d_in, const int* in_sizes, int n_in,
                              void* d_out, int out_size, void* d_ws, size_t ws_size,
                              hipStream_t stream) {
    const float* pred = (const float*)d_in[0];
    const float* tbox = (const float*)d_in[1];
    const float* tcls = (const float*)d_in[2];
    const void*  mask = d_in[3];
    const int ncells = in_sizes[3];            // N*S*S
    const int N = ncells / (14 * 14);

    float* acc = (float*)d_ws;
    int*  flag = (int*)((char*)d_ws + 32);

    int nwords = ((ncells < 65536) ? ncells : 65536) / 4;   // safe even if mask is 1 byte/elem
    detect_mask_kernel<<<1, 256, 0, stream>>>((const unsigned int*)mask, nwords, acc, flag);

    const int blocks = 2048;                   // grid-stride, ~3 cells/thread
    yolo_loss_kernel<<<blocks, 256, 0, stream>>>(pred, tbox, tcls, mask, flag, acc, ncells);

    finalize_kernel<<<1, 64, 0, stream>>>(acc, (float*)d_out, 1.0f / (float)N);
}

// Round 2
// 119.904 us; speedup vs baseline: 3.8461x; 3.8461x over previous
//
#include <hip/hip_runtime.h>

// YOLO loss: N=8192, S=14, B=2, C=20. ncells = N*S*S = 1,605,632.
// d_in[0] pred (ncells*30 f32), d_in[1] tbox (ncells*4 f32),
// d_in[2] tcls (ncells*20 f32), d_in[3] mask (ncells, dtype detected at runtime)
// d_out: 5 f32 = [total, reg, contain, noobj, cls] / N

#define L_COORD 5.0f
#define L_NOOBJ 0.5f
#define TILE 256

// ws layout: float accumulators at float-offsets 0,32,64,96 (128B apart:
// reg, contain, noobj, cls); int flag at byte offset 512.

__global__ void detect_mask_kernel(const unsigned int* __restrict__ w, int nwords,
                                   float* __restrict__ acc, int* __restrict__ flag) {
    __shared__ int s_int, s_flt;
    if (threadIdx.x == 0) {
        s_int = 1; s_flt = 1;
        acc[0] = 0.f; acc[32] = 0.f; acc[64] = 0.f; acc[96] = 0.f;
    }
    __syncthreads();
    int okInt = 1, okFlt = 1;
    for (int i = threadIdx.x; i < nwords; i += blockDim.x) {
        unsigned int v = w[i];
        okInt = okInt && (v == 0u || v == 1u);
        okFlt = okFlt && (v == 0u || v == 0x3F800000u);
    }
    if (!okInt) atomicAnd(&s_int, 0);
    if (!okFlt) atomicAnd(&s_flt, 0);
    __syncthreads();
    if (threadIdx.x == 0) *flag = s_int ? 1 : (s_flt ? 2 : 0);
}

__launch_bounds__(256)
__global__ void yolo_loss_kernel(const float* __restrict__ pred,
                                 const float* __restrict__ tbox,
                                 const float* __restrict__ tcls,
                                 const void* __restrict__ mask,
                                 const int* __restrict__ flag_p,
                                 float* __restrict__ acc,
                                 int ncells) {
    __shared__ float sp[TILE * 30];           // 30720 B
    __shared__ float red[4][4];

    const int flg = *flag_p;                  // uniform
    const float invS = 1.0f / 14.0f;

    const int tile = blockIdx.x;
    const size_t base = (size_t)tile * TILE;
    int nvalid = ncells - (int)base;
    if (nvalid > TILE) nvalid = TILE;

    // ---- coalesced stage of pred tile into LDS ----
    if (nvalid == TILE) {
        const float4* gp = (const float4*)(pred + base * 30);
        float4* sp4 = (float4*)sp;
        #pragma unroll
        for (int i = 0; i < 8; ++i) {
            int idx = threadIdx.x + (i << 8);
            if (idx < (TILE * 30 / 4)) sp4[idx] = gp[idx];
        }
    } else {
        for (int i = threadIdx.x; i < nvalid * 30; i += blockDim.x)
            sp[i] = pred[base * 30 + i];
    }
    __syncthreads();

    float a_reg = 0.f, a_con = 0.f, a_noo = 0.f, a_cls = 0.f;

    if ((int)threadIdx.x < nvalid) {
        const int c = (int)base + threadIdx.x;
        float f;
        if (flg == 1)      f = (((const int*)mask)[c] != 0) ? 1.0f : 0.0f;
        else if (flg == 2) f = ((const float*)mask)[c];
        else               f = (((const unsigned char*)mask)[c] != 0) ? 1.0f : 0.0f;

        const float* my = sp + threadIdx.x * 30;
        float px0 = my[0], py0 = my[1], pw0 = my[2], ph0 = my[3], cf0 = my[4];
        float px1 = my[5], py1 = my[6], pw1 = my[7], ph1 = my[8], cf1 = my[9];

        a_noo = (1.0f - f) * (cf0 * cf0 + cf1 * cf1);

        if (f != 0.0f) {
            // class loss: LDS pred[10..29] vs gathered tcls
            const float4* tc4 = (const float4*)(tcls + (size_t)c * 20);  // 80B/cell, 16B aligned
            float cl = 0.f;
            #pragma unroll
            for (int i = 0; i < 5; ++i) {
                float4 t = tc4[i];
                float d0 = my[10 + 4 * i + 0] - t.x;
                float d1 = my[10 + 4 * i + 1] - t.y;
                float d2 = my[10 + 4 * i + 2] - t.z;
                float d3 = my[10 + 4 * i + 3] - t.w;
                cl += d0 * d0 + d1 * d1 + d2 * d2 + d3 * d3;
            }
            a_cls = f * cl;

            float4 tb = ((const float4*)tbox)[c];
            float tx1 = tb.x * invS - 0.5f * tb.z;
            float ty1 = tb.y * invS - 0.5f * tb.w;
            float tx2 = tb.x * invS + 0.5f * tb.z;
            float ty2 = tb.y * invS + 0.5f * tb.w;
            float ta  = (tx2 - tx1) * (ty2 - ty1);

            // IoU box 0
            float x1 = px0 * invS - 0.5f * pw0, y1 = py0 * invS - 0.5f * ph0;
            float x2 = px0 * invS + 0.5f * pw0, y2 = py0 * invS + 0.5f * ph0;
            float lx = fmaxf(x1, tx1), ly = fmaxf(y1, ty1);
            float rx = fminf(x2, tx2), ry = fminf(y2, ty2);
            float wx = fmaxf(rx - lx, 0.f), wy = fmaxf(ry - ly, 0.f);
            float inter = wx * wy;
            float pa = (x2 - x1) * (y2 - y1);
            float iou0 = inter / (pa + ta - inter);
            // IoU box 1
            x1 = px1 * invS - 0.5f * pw1; y1 = py1 * invS - 0.5f * ph1;
            x2 = px1 * invS + 0.5f * pw1; y2 = py1 * invS + 0.5f * ph1;
            lx = fmaxf(x1, tx1); ly = fmaxf(y1, ty1);
            rx = fminf(x2, tx2); ry = fminf(y2, ty2);
            wx = fmaxf(rx - lx, 0.f); wy = fmaxf(ry - ly, 0.f);
            inter = wx * wy;
            pa = (x2 - x1) * (y2 - y1);
            float iou1 = inter / (pa + ta - inter);

            // jnp.argmax: first index on tie -> box1 wins only if strictly greater
            int best = (iou1 > iou0) ? 1 : 0;
            float miou = fmaxf(iou0, iou1);

            float bx = best ? px1 : px0, by = best ? py1 : py0;
            float bw = best ? pw1 : pw0, bh = best ? ph1 : ph0;
            float bc = best ? cf1 : cf0;

            float dx = bx - tb.x, dy = by - tb.y;
            float sw = sqrtf(fmaxf(bw, 0.f)) - sqrtf(fmaxf(tb.z, 0.f));
            float sh = sqrtf(fmaxf(bh, 0.f)) - sqrtf(fmaxf(tb.w, 0.f));
            a_reg = f * (dx * dx + dy * dy + sw * sw + sh * sh);
            float dc = bc - miou;
            a_con = f * dc * dc;
        }
    }

    // ---- wave reduce (64 lanes), then block reduce, one atomic set/block ----
    #pragma unroll
    for (int off = 32; off > 0; off >>= 1) {
        a_reg += __shfl_down(a_reg, off, 64);
        a_con += __shfl_down(a_con, off, 64);
        a_noo += __shfl_down(a_noo, off, 64);
        a_cls += __shfl_down(a_cls, off, 64);
    }
    const int wid = threadIdx.x >> 6, lane = threadIdx.x & 63;
    if (lane == 0) {
        red[wid][0] = a_reg; red[wid][1] = a_con;
        red[wid][2] = a_noo; red[wid][3] = a_cls;
    }
    __syncthreads();
    if (threadIdx.x == 0) {
        float r = 0.f, co = 0.f, no = 0.f, cl = 0.f;
        #pragma unroll
        for (int w = 0; w < 4; ++w) {
            r += red[w][0]; co += red[w][1]; no += red[w][2]; cl += red[w][3];
        }
        atomicAdd(&acc[0],  r);
        atomicAdd(&acc[32], co);
        atomicAdd(&acc[64], no);
        atomicAdd(&acc[96], cl);
    }
}

__global__ void finalize_kernel(const float* __restrict__ acc, float* __restrict__ out, float inv_n) {
    if (threadIdx.x == 0) {
        float reg = acc[0], con = acc[32], noo = acc[64], cls = acc[96];
        float total = cls + L_NOOBJ * noo + L_COORD * reg + con;
        out[0] = total * inv_n;
        out[1] = reg   * inv_n;
        out[2] = con   * inv_n;
        out[3] = noo   * inv_n;
        out[4] = cls   * inv_n;
    }
}

extern "C" void kernel_launch(void* const* d_in, const int* in_sizes, int n_in,
                              void* d_out, int out_size, void* d_ws, size_t ws_size,
                              hipStream_t stream) {
    const float* pred = (const float*)d_in[0];
    const float* tbox = (const float*)d_in[1];
    const float* tcls = (const float*)d_in[2];
    const void*  mask = d_in[3];
    const int ncells = in_sizes[3];            // N*S*S
    const int N = ncells / (14 * 14);

    float* acc = (float*)d_ws;
    int*  flag = (int*)((char*)d_ws + 512);

    int nwords = ((ncells < 65536) ? ncells : 65536) / 4;   // safe even if mask is 1 byte/elem
    detect_mask_kernel<<<1, 256, 0, stream>>>((const unsigned int*)mask, nwords, acc, flag);

    const int ntiles = (ncells + TILE - 1) / TILE;          // 6272
    yolo_loss_kernel<<<ntiles, 256, 0, stream>>>(pred, tbox, tcls, mask, flag, acc, ncells);

    finalize_kernel<<<1, 64, 0, stream>>>(acc, (float*)d_out, 1.0f / (float)N);
}